// Round 2
// baseline (289.751 us; speedup 1.0000x reference)
//
#include <hip/hip_runtime.h>

#define BATCH   4096
#define IN_DIM  2048
#define OUT_DIM 14951
#define ROWS    4              // rows per block
#define NT      512            // 8 waves; 128 threads (2 waves) per row
#define STRIDE  2052           // 2048 + 4 pad floats for the wrap window
#define EPS     1e-12f

typedef float nfloat4 __attribute__((ext_vector_type(4)));   // native vec4 for nontemporal stores

// out[b, j] = -scale/||x_b|| * FWHT2048(x_b)[j & 2047] + bias[j]
// H[i,j] = (-1)^popc(i&j), i < 2048 => column j == column (j & 2047).
//
// FWHT: h=1..8 in registers (16 consecutive elems/thread), h=16..512 via
// __shfl_xor butterflies (partner lane t^(h/16), all within the 64-lane wave,
// no barriers), h=1024 via one LDS exchange across the row's two waves.
//
// Epilogue: for row rr take j = rr + 4k. Then:
//   store addr (b0+rr)*14951 + j == 0 (mod 4)  -> aligned dwordx4 stores
//   m4 = (4k) & 2047 is 4-aligned and row-independent -> conflict-free
//   ds_read_b128 window + compile-time selects; one aligned bias float4 pair
//   shared by all 4 rows. 28 leftover scalars per block handled at the end.
__global__ __launch_bounds__(NT, 8) void HadamardClassifier_44487271252814_kernel(
    const float* __restrict__ x,
    const float* __restrict__ scale,
    const float* __restrict__ bias,
    float* __restrict__ out)
{
    __shared__ float y[ROWS * STRIDE];     // 32,832 B
    __shared__ float rss[ROWS * 2];
    __shared__ float srow[ROWS];

    const int tid = threadIdx.x;
    const int r   = tid >> 7;              // row within block (0..3)
    const int t   = tid & 127;             // thread within row (2 waves)
    const int b0  = blockIdx.x * ROWS;

    // ---- load 16 consecutive elements [16t, 16t+16) of row r
    const float4* xv = reinterpret_cast<const float4*>(x + (size_t)(b0 + r) * IN_DIM) + 4 * t;
    float4 v0 = xv[0], v1 = xv[1], v2 = xv[2], v3 = xv[3];
    float a[16] = { v0.x, v0.y, v0.z, v0.w, v1.x, v1.y, v1.z, v1.w,
                    v2.x, v2.y, v2.z, v2.w, v3.x, v3.y, v3.z, v3.w };

    // ---- sum of squares for L2 norm
    float ss = 0.f;
    #pragma unroll
    for (int k = 0; k < 16; ++k) ss += a[k] * a[k];
    #pragma unroll
    for (int off = 32; off > 0; off >>= 1) ss += __shfl_down(ss, off, 64);
    if ((tid & 63) == 0) rss[tid >> 6] = ss;   // waves 2r, 2r+1 belong to row r

    // ---- FWHT stages h=1,2,4,8 in registers
    #pragma unroll
    for (int h = 1; h < 16; h <<= 1) {
        #pragma unroll
        for (int g = 0; g < 16; g += 2 * h) {
            #pragma unroll
            for (int k = 0; k < h; ++k) {
                float u = a[g + k], w = a[g + k + h];
                a[g + k]     = u + w;
                a[g + k + h] = u - w;
            }
        }
    }

    // ---- FWHT stages h=16..512 via shfl_xor (element j=16t+k; bit log2(h) of j
    //      is bit s of t; partner lane t^(1<<s) is in the same 64-lane wave)
    #pragma unroll
    for (int s = 0; s < 6; ++s) {
        const float sgn = (t & (1 << s)) ? -1.0f : 1.0f;   // set bit -> holds "hi"
        #pragma unroll
        for (int k = 0; k < 16; ++k) {
            float recv = __shfl_xor(a[k], 1 << s, 64);
            a[k] = fmaf(sgn, a[k], recv);                  // lo: own+recv, hi: recv-own
        }
    }

    // ---- h=1024: cross-wave exchange through LDS
    float* yr = y + r * STRIDE;
    #pragma unroll
    for (int k = 0; k < 4; ++k)
        *reinterpret_cast<float4*>(&yr[16 * t + 4 * k]) =
            make_float4(a[4 * k], a[4 * k + 1], a[4 * k + 2], a[4 * k + 3]);
    __syncthreads();                                       // barrier A

    if (tid < ROWS)
        srow[tid] = -scale[0] * rsqrtf(fmaxf(rss[2 * tid] + rss[2 * tid + 1], EPS));

    const int tp = t ^ 64;                                 // partner block owner
    float p[16];
    #pragma unroll
    for (int k = 0; k < 4; ++k) {
        float4 w = *reinterpret_cast<const float4*>(&yr[16 * tp + 4 * k]);
        p[4 * k] = w.x; p[4 * k + 1] = w.y; p[4 * k + 2] = w.z; p[4 * k + 3] = w.w;
    }
    __syncthreads();                                       // barrier B: reads done before overwrite

    const float sg = (t < 64) ? 1.0f : -1.0f;              // t<64 holds "lo" of the pair
    #pragma unroll
    for (int k = 0; k < 16; ++k) a[k] = fmaf(sg, a[k], p[k]);

    #pragma unroll
    for (int k = 0; k < 4; ++k)
        *reinterpret_cast<float4*>(&yr[16 * t + 4 * k]) =
            make_float4(a[4 * k], a[4 * k + 1], a[4 * k + 2], a[4 * k + 3]);
    if (t == 0)                                            // wrap pad: y[2048..2051] = y[0..3]
        *reinterpret_cast<float4*>(&yr[2048]) = make_float4(a[0], a[1], a[2], a[3]);
    __syncthreads();                                       // barrier C

    // ---- epilogue: 4 aligned vec4 outputs per k, shared bias window
    const float sv0 = srow[0], sv1 = srow[1], sv2 = srow[2], sv3 = srow[3];
    const float* y0p = y;
    const float* y1p = y + STRIDE;
    const float* y2p = y + 2 * STRIDE;
    const float* y3p = y + 3 * STRIDE;

    for (int k = tid; k < (OUT_DIM >> 2) - 1; k += NT) {   // k < 3736
        const int e  = 4 * k;
        const int m4 = e & (IN_DIM - 1);                   // 4-aligned, 0..2044, same for all rows
        const float4 blo = *reinterpret_cast<const float4*>(&bias[e]);
        const float4 bhi = *reinterpret_cast<const float4*>(&bias[e + 4]);   // e+7 <= 14947: in-bounds
        const size_t ob = (size_t)b0 * OUT_DIM + e;

        {   // row 0: j = e
            const float4 w0 = *reinterpret_cast<const float4*>(&y0p[m4]);
            nfloat4 o;
            o.x = fmaf(sv0, w0.x, blo.x);
            o.y = fmaf(sv0, w0.y, blo.y);
            o.z = fmaf(sv0, w0.z, blo.z);
            o.w = fmaf(sv0, w0.w, blo.w);
            __builtin_nontemporal_store(o, reinterpret_cast<nfloat4*>(&out[ob]));
        }
        {   // row 1: j = e+1; store offset ob + OUT_DIM + 1 == 0 (mod 4)
            const float4 w0 = *reinterpret_cast<const float4*>(&y1p[m4]);
            const float4 w1 = *reinterpret_cast<const float4*>(&y1p[m4 + 4]);
            nfloat4 o;
            o.x = fmaf(sv1, w0.y, blo.y);
            o.y = fmaf(sv1, w0.z, blo.z);
            o.z = fmaf(sv1, w0.w, blo.w);
            o.w = fmaf(sv1, w1.x, bhi.x);
            __builtin_nontemporal_store(o, reinterpret_cast<nfloat4*>(&out[ob + OUT_DIM + 1]));
        }
        {   // row 2: j = e+2
            const float4 w0 = *reinterpret_cast<const float4*>(&y2p[m4]);
            const float4 w1 = *reinterpret_cast<const float4*>(&y2p[m4 + 4]);
            nfloat4 o;
            o.x = fmaf(sv2, w0.z, blo.z);
            o.y = fmaf(sv2, w0.w, blo.w);
            o.z = fmaf(sv2, w1.x, bhi.x);
            o.w = fmaf(sv2, w1.y, bhi.y);
            __builtin_nontemporal_store(o, reinterpret_cast<nfloat4*>(&out[ob + 2 * OUT_DIM + 2]));
        }
        {   // row 3: j = e+3
            const float4 w0 = *reinterpret_cast<const float4*>(&y3p[m4]);
            const float4 w1 = *reinterpret_cast<const float4*>(&y3p[m4 + 4]);
            nfloat4 o;
            o.x = fmaf(sv3, w0.w, blo.w);
            o.y = fmaf(sv3, w1.x, bhi.x);
            o.z = fmaf(sv3, w1.y, bhi.y);
            o.w = fmaf(sv3, w1.z, bhi.z);
            __builtin_nontemporal_store(o, reinterpret_cast<nfloat4*>(&out[ob + 3 * OUT_DIM + 3]));
        }
    }

    // ---- leftovers: per row rr, heads j in [0, rr) and tails j in [14944+rr, 14950]
    //      => 7 scalars per row, 28 per block.
    if (tid < 28) {
        const int rr  = tid / 7;
        const int idx = tid - rr * 7;
        const int j   = (idx < rr) ? idx : (14944 + idx);
        out[(size_t)(b0 + rr) * OUT_DIM + j] =
            fmaf(srow[rr], y[rr * STRIDE + (j & (IN_DIM - 1))], bias[j]);
    }
}

extern "C" void kernel_launch(void* const* d_in, const int* in_sizes, int n_in,
                              void* d_out, int out_size, void* d_ws, size_t ws_size,
                              hipStream_t stream) {
    const float* x     = (const float*)d_in[0];
    const float* scale = (const float*)d_in[1];
    const float* bias  = (const float*)d_in[2];
    float* out = (float*)d_out;

    hipLaunchKernelGGL(HadamardClassifier_44487271252814_kernel,
                       dim3(BATCH / ROWS), dim3(NT), 0, stream,
                       x, scale, bias, out);
}